// Round 4
// baseline (52.658 us; speedup 1.0000x reference)
//
#include <hip/hip_runtime.h>
#include <hip/hip_bf16.h>

// mIoU loss, histogram formulation, two-stage (no global atomics).
// Round-1 lesson: global atomics on 60 addrs -> 313us.
// Round-2/3 lesson: identical 42us for RMW vs LDS-atomic histogram =>
//   not LDS-bound. VGPR_Count 12-16 shows the compiler serialized each
//   iteration (load -> vmcnt(0) -> process): latency-bound, no MLP.
// Round-4 fix: explicit 4-deep unroll, 8 int4 loads in flight before any
//   LDS update; block 256 (20KB LDS, 8 blocks/CU); grid 2048; no tight
//   launch_bounds so the allocator keeps ~40-60 VGPRs.

#define NB      20
#define BLK     256
#define GRIDH   2048
#define PSTRIDE 64   // padded row per block in workspace

__device__ __forceinline__ void process_pix(int p, int t, unsigned* s_col) {
    // packed fields: bits 0..9 pred_count, 10..19 target_count, 20..29 inter
    unsigned m = (unsigned)(p == t);
    atomicAdd(&s_col[p * BLK], 1u + (m << 20));  // pred count + intersection
    atomicAdd(&s_col[t * BLK], 1u << 10);        // target count
}

__device__ __forceinline__ void process_vec(int4 pv, int4 tv, unsigned* s_col) {
    process_pix(pv.x, tv.x, s_col);
    process_pix(pv.y, tv.y, s_col);
    process_pix(pv.z, tv.z, s_col);
    process_pix(pv.w, tv.w, s_col);
}

__global__ __launch_bounds__(BLK) void miou_hist_kernel(
        const int4* __restrict__ preds, const int4* __restrict__ targs,
        unsigned* __restrict__ partials, int n4) {
    __shared__ unsigned s_hist[NB * BLK];
    const int tid = threadIdx.x;

    #pragma unroll
    for (int c = 0; c < NB; ++c) s_hist[c * BLK + tid] = 0u;
    __syncthreads();

    unsigned* s_col = &s_hist[tid];
    const int stride = gridDim.x * BLK;
    int i = blockIdx.x * BLK + tid;

    // Main loop: 4 iterations deep, all 8 loads issued before first use.
    for (; i + 3 * stride < n4; i += 4 * stride) {
        int4 pv0 = preds[i];
        int4 pv1 = preds[i + stride];
        int4 pv2 = preds[i + 2 * stride];
        int4 pv3 = preds[i + 3 * stride];
        int4 tv0 = targs[i];
        int4 tv1 = targs[i + stride];
        int4 tv2 = targs[i + 2 * stride];
        int4 tv3 = targs[i + 3 * stride];
        process_vec(pv0, tv0, s_col);
        process_vec(pv1, tv1, s_col);
        process_vec(pv2, tv2, s_col);
        process_vec(pv3, tv3, s_col);
    }
    // Tail (empty for the 16M-pixel shape).
    for (; i < n4; i += stride) {
        int4 pv = preds[i];
        int4 tv = targs[i];
        process_vec(pv, tv, s_col);
    }
    __syncthreads();

    // Block reduction: 4 waves, wave w handles classes w, w+4, ..., <NB.
    const int wid  = tid >> 6;
    const int lane = tid & 63;
    unsigned* dst = &partials[(size_t)blockIdx.x * PSTRIDE];
    for (int c = wid; c < NB; c += (BLK / 64)) {
        unsigned sp = 0, st = 0, si = 0;
        #pragma unroll
        for (int k = 0; k < BLK / 64; ++k) {
            unsigned v = s_hist[c * BLK + k * 64 + lane];
            sp += v & 1023u;
            st += (v >> 10) & 1023u;
            si += (v >> 20) & 1023u;
        }
        #pragma unroll
        for (int off = 32; off > 0; off >>= 1) {
            sp += __shfl_xor(sp, off);
            st += __shfl_xor(st, off);
            si += __shfl_xor(si, off);
        }
        if (lane == 0) {
            dst[c]          = sp;
            dst[NB + c]     = st;
            dst[2 * NB + c] = si;
        }
    }
}

// One block, 1024 threads. Column col (0..63) summed by 16 sub-threads.
__global__ __launch_bounds__(1024) void miou_reduce_kernel(
        const unsigned* __restrict__ partials, int nblocks,
        const int* __restrict__ nb_ptr, const int* __restrict__ smooth_ptr,
        float* __restrict__ out) {
    __shared__ unsigned s_sum[16][PSTRIDE];
    const int col = threadIdx.x & 63;
    const int sub = threadIdx.x >> 6;

    unsigned acc = 0;
    for (int r = sub; r < nblocks; r += 16)
        acc += partials[(size_t)r * PSTRIDE + col];
    s_sum[sub][col] = acc;
    __syncthreads();

    if (threadIdx.x < PSTRIDE) {
        unsigned tot = 0;
        #pragma unroll
        for (int k = 0; k < 16; ++k) tot += s_sum[k][threadIdx.x];
        s_sum[0][threadIdx.x] = tot;
    }
    __syncthreads();

    if (threadIdx.x == 0) {
        const int   nb = *nb_ptr;
        const float s  = (float)(*smooth_ptr);
        float acc_iou = 0.0f;
        for (int c = 0; c < nb && c < NB; ++c) {
            float pc    = (float)s_sum[0][c];
            float tc    = (float)s_sum[0][NB + c];
            float inter = (float)s_sum[0][2 * NB + c];
            float uni   = pc + tc - inter;
            acc_iou += (inter + s) / (uni + s);
        }
        out[0] = 1.0f - acc_iou / (float)nb;
    }
}

extern "C" void kernel_launch(void* const* d_in, const int* in_sizes, int n_in,
                              void* d_out, int out_size, void* d_ws, size_t ws_size,
                              hipStream_t stream) {
    const int4* preds      = (const int4*)d_in[0];
    const int4* targs      = (const int4*)d_in[1];
    const int*  nb_ptr     = (const int*)d_in[2];
    const int*  smooth_ptr = (const int*)d_in[3];
    float*      out        = (float*)d_out;

    int n  = in_sizes[0];
    int n4 = n >> 2;  // 16M pixels, divisible by 4

    unsigned* partials = (unsigned*)d_ws;

    int grid = GRIDH;
    int max_grid = (n4 + BLK - 1) / BLK;
    if (grid > max_grid) grid = max_grid;
    size_t need_per_block = PSTRIDE * sizeof(unsigned);
    if ((size_t)grid * need_per_block > ws_size)
        grid = (int)(ws_size / need_per_block);

    miou_hist_kernel<<<grid, BLK, 0, stream>>>(preds, targs, partials, n4);
    miou_reduce_kernel<<<1, 1024, 0, stream>>>(partials, grid, nb_ptr, smooth_ptr, out);
}

// Round 5
// 40.404 us; speedup vs baseline: 1.3033x; 1.3033x over previous
//
#include <hip/hip_runtime.h>
#include <hip/hip_bf16.h>

// mIoU loss, histogram formulation, two-stage (no global atomics).
// Round-1: global atomics on 60 addrs -> 313us (serialized far-atomics).
// Round-2/3: RMW vs LDS-atomic identical 42us -> LDS op mix not the wall.
// Round-4: compiler sank loads (VGPR 28), no MLP -> latency-bound at
//   ~1-2 loads in flight per CU (Little's law from 134MB/45us/230ns).
// Round-5: force MLP. Fully unroll the 8 strided int4-pairs per thread,
//   issue all 16 global loads back-to-back, pin with sched_barrier(0)
//   so they cannot be sunk. 64 VGPRs of data in flight per wave.

#define NB      20
#define BLK     256
#define GRIDH   2048
#define PSTRIDE 64   // padded row per block in workspace (16 int4)

__device__ __forceinline__ void process_pix(int p, int t, unsigned* s_col) {
    // packed fields: bits 0..9 pred_count, 10..19 target_count, 20..29 inter
    // per-thread per-class max = 32 pixels -> fits 10 bits.
    unsigned m = (unsigned)(p == t);
    atomicAdd(&s_col[p * BLK], 1u + (m << 20));  // pred count + intersection
    atomicAdd(&s_col[t * BLK], 1u << 10);        // target count
}

__device__ __forceinline__ void process_vec(int4 pv, int4 tv, unsigned* s_col) {
    process_pix(pv.x, tv.x, s_col);
    process_pix(pv.y, tv.y, s_col);
    process_pix(pv.z, tv.z, s_col);
    process_pix(pv.w, tv.w, s_col);
}

__global__ __launch_bounds__(BLK) void miou_hist_kernel(
        const int4* __restrict__ preds, const int4* __restrict__ targs,
        unsigned* __restrict__ partials, int n4) {
    __shared__ unsigned s_hist[NB * BLK];
    const int tid = threadIdx.x;

    #pragma unroll
    for (int c = 0; c < NB; ++c) s_hist[c * BLK + tid] = 0u;
    __syncthreads();

    unsigned* s_col = &s_hist[tid];
    const int stride = gridDim.x * BLK;
    int i = blockIdx.x * BLK + tid;

    if (i + 7 * stride < n4) {
        // Fast path (exact for the 16M-pixel shape): all 16 loads issued
        // before any consumption; sched_barrier(0) forbids sinking them.
        int4 p0 = preds[i];
        int4 p1 = preds[i + stride];
        int4 p2 = preds[i + 2 * stride];
        int4 p3 = preds[i + 3 * stride];
        int4 p4 = preds[i + 4 * stride];
        int4 p5 = preds[i + 5 * stride];
        int4 p6 = preds[i + 6 * stride];
        int4 p7 = preds[i + 7 * stride];
        int4 t0 = targs[i];
        int4 t1 = targs[i + stride];
        int4 t2 = targs[i + 2 * stride];
        int4 t3 = targs[i + 3 * stride];
        int4 t4 = targs[i + 4 * stride];
        int4 t5 = targs[i + 5 * stride];
        int4 t6 = targs[i + 6 * stride];
        int4 t7 = targs[i + 7 * stride];
        __builtin_amdgcn_sched_barrier(0);
        process_vec(p0, t0, s_col);
        process_vec(p1, t1, s_col);
        process_vec(p2, t2, s_col);
        process_vec(p3, t3, s_col);
        process_vec(p4, t4, s_col);
        process_vec(p5, t5, s_col);
        process_vec(p6, t6, s_col);
        process_vec(p7, t7, s_col);
        i += 8 * stride;
    }
    // General/tail path.
    for (; i < n4; i += stride) {
        int4 pv = preds[i];
        int4 tv = targs[i];
        process_vec(pv, tv, s_col);
    }
    __syncthreads();

    // Block reduction: 4 waves, wave w handles classes w, w+4, ..., <NB.
    const int wid  = tid >> 6;
    const int lane = tid & 63;
    unsigned* dst = &partials[(size_t)blockIdx.x * PSTRIDE];
    for (int c = wid; c < NB; c += (BLK / 64)) {
        unsigned sp = 0, st = 0, si = 0;
        #pragma unroll
        for (int k = 0; k < BLK / 64; ++k) {
            unsigned v = s_hist[c * BLK + k * 64 + lane];
            sp += v & 1023u;
            st += (v >> 10) & 1023u;
            si += (v >> 20) & 1023u;
        }
        #pragma unroll
        for (int off = 32; off > 0; off >>= 1) {
            sp += __shfl_xor(sp, off);
            st += __shfl_xor(st, off);
            si += __shfl_xor(si, off);
        }
        if (lane == 0) {
            dst[c]          = sp;
            dst[NB + c]     = st;
            dst[2 * NB + c] = si;
        }
    }
}

// One block, 1024 threads. partials = nblocks rows x 16 int4 (coalesced).
__global__ __launch_bounds__(1024) void miou_reduce_kernel(
        const unsigned* __restrict__ partials, int nblocks,
        const int* __restrict__ nb_ptr, const int* __restrict__ smooth_ptr,
        float* __restrict__ out) {
    __shared__ unsigned s_tot[PSTRIDE];
    if (threadIdx.x < PSTRIDE) s_tot[threadIdx.x] = 0u;
    __syncthreads();

    const int col4 = threadIdx.x & 15;   // int4 column 0..15
    const int seg  = threadIdx.x >> 4;   // 64 row-segments
    const int4* p4 = (const int4*)partials;

    unsigned ax = 0, ay = 0, az = 0, aw = 0;
    #pragma unroll 8
    for (int r = seg; r < nblocks; r += 64) {
        int4 v = p4[r * 16 + col4];      // addr = tid + k*1024: coalesced
        ax += (unsigned)v.x; ay += (unsigned)v.y;
        az += (unsigned)v.z; aw += (unsigned)v.w;
    }
    atomicAdd(&s_tot[col4 * 4 + 0], ax);
    atomicAdd(&s_tot[col4 * 4 + 1], ay);
    atomicAdd(&s_tot[col4 * 4 + 2], az);
    atomicAdd(&s_tot[col4 * 4 + 3], aw);
    __syncthreads();

    if (threadIdx.x == 0) {
        const int   nb = *nb_ptr;
        const float s  = (float)(*smooth_ptr);
        float acc_iou = 0.0f;
        for (int c = 0; c < nb && c < NB; ++c) {
            float pc    = (float)s_tot[c];
            float tc    = (float)s_tot[NB + c];
            float inter = (float)s_tot[2 * NB + c];
            float uni   = pc + tc - inter;
            acc_iou += (inter + s) / (uni + s);
        }
        out[0] = 1.0f - acc_iou / (float)nb;
    }
}

extern "C" void kernel_launch(void* const* d_in, const int* in_sizes, int n_in,
                              void* d_out, int out_size, void* d_ws, size_t ws_size,
                              hipStream_t stream) {
    const int4* preds      = (const int4*)d_in[0];
    const int4* targs      = (const int4*)d_in[1];
    const int*  nb_ptr     = (const int*)d_in[2];
    const int*  smooth_ptr = (const int*)d_in[3];
    float*      out        = (float*)d_out;

    int n  = in_sizes[0];
    int n4 = n >> 2;  // 16M pixels, divisible by 4

    unsigned* partials = (unsigned*)d_ws;

    int grid = GRIDH;
    int max_grid = (n4 + BLK - 1) / BLK;
    if (grid > max_grid) grid = max_grid;
    size_t need_per_block = PSTRIDE * sizeof(unsigned);
    if ((size_t)grid * need_per_block > ws_size)
        grid = (int)(ws_size / need_per_block);

    miou_hist_kernel<<<grid, BLK, 0, stream>>>(preds, targs, partials, n4);
    miou_reduce_kernel<<<1, 1024, 0, stream>>>(partials, grid, nb_ptr, smooth_ptr, out);
}

// Round 6
// 37.657 us; speedup vs baseline: 1.3984x; 1.0729x over previous
//
#include <hip/hip_runtime.h>
#include <hip/hip_bf16.h>

// mIoU loss, histogram formulation, two-stage (no global atomics).
// Ledger:
//  R1: global atomics on 60 addrs -> 313us (serialized far-atomics).
//  R2~R3: plain-RMW vs LDS-atomic histogram identical 42us -> DS op mix
//         not the wall. L3-resident replays same time -> not BW-bound.
//  R4: 4-deep unroll: compiler sank loads (VGPR 28) -> no MLP, 52us.
//  R5: sched_barrier(0) pin: VGPR 36 -> loads STILL not held live;
//         experiment void. Latency theory still untested.
//  R6: keep-alive asm ("v" operand use + "memory" clobber) after all 16
//      loads: the compiler CANNOT kill these live ranges. 16 loads issued
//      back-to-back, consumed as they arrive (vmcnt-counted). VGPR_Count
//      >= 80 is the validity check for this experiment.

#define NB      20
#define BLK     256
#define GRIDH   2048
#define PSTRIDE 64   // padded row per block in workspace (16 int4)

#define KEEP4(v) asm volatile("" :: "v"((v).x), "v"((v).y), "v"((v).z), "v"((v).w) : "memory")

__device__ __forceinline__ void process_pix(int p, int t, unsigned* s_col) {
    // packed fields: bits 0..9 pred_count, 10..19 target_count, 20..29 inter
    // per-thread per-class max = 32 pixels -> fits 10 bits.
    unsigned m = (unsigned)(p == t);
    atomicAdd(&s_col[p * BLK], 1u + (m << 20));  // pred count + intersection
    atomicAdd(&s_col[t * BLK], 1u << 10);        // target count
}

__device__ __forceinline__ void process_vec(int4 pv, int4 tv, unsigned* s_col) {
    process_pix(pv.x, tv.x, s_col);
    process_pix(pv.y, tv.y, s_col);
    process_pix(pv.z, tv.z, s_col);
    process_pix(pv.w, tv.w, s_col);
}

__global__ __launch_bounds__(BLK) void miou_hist_kernel(
        const int4* __restrict__ preds, const int4* __restrict__ targs,
        unsigned* __restrict__ partials, int n4) {
    __shared__ unsigned s_hist[NB * BLK];
    const int tid = threadIdx.x;

    #pragma unroll
    for (int c = 0; c < NB; ++c) s_hist[c * BLK + tid] = 0u;
    __syncthreads();

    unsigned* s_col = &s_hist[tid];
    const int stride = gridDim.x * BLK;
    int i = blockIdx.x * BLK + tid;

    if (i + 7 * stride < n4) {
        // Exact path for the 16M-pixel shape: all 16 loads issued
        // back-to-back; keep-alive asm pins every result live.
        int4 p0 = preds[i];
        int4 p1 = preds[i + stride];
        int4 p2 = preds[i + 2 * stride];
        int4 p3 = preds[i + 3 * stride];
        int4 p4 = preds[i + 4 * stride];
        int4 p5 = preds[i + 5 * stride];
        int4 p6 = preds[i + 6 * stride];
        int4 p7 = preds[i + 7 * stride];
        int4 t0 = targs[i];
        int4 t1 = targs[i + stride];
        int4 t2 = targs[i + 2 * stride];
        int4 t3 = targs[i + 3 * stride];
        int4 t4 = targs[i + 4 * stride];
        int4 t5 = targs[i + 5 * stride];
        int4 t6 = targs[i + 6 * stride];
        int4 t7 = targs[i + 7 * stride];
        KEEP4(p0); KEEP4(t0);
        KEEP4(p1); KEEP4(t1);
        KEEP4(p2); KEEP4(t2);
        KEEP4(p3); KEEP4(t3);
        KEEP4(p4); KEEP4(t4);
        KEEP4(p5); KEEP4(t5);
        KEEP4(p6); KEEP4(t6);
        KEEP4(p7); KEEP4(t7);
        process_vec(p0, t0, s_col);
        process_vec(p1, t1, s_col);
        process_vec(p2, t2, s_col);
        process_vec(p3, t3, s_col);
        process_vec(p4, t4, s_col);
        process_vec(p5, t5, s_col);
        process_vec(p6, t6, s_col);
        process_vec(p7, t7, s_col);
        i += 8 * stride;
    }
    // General/tail path (empty for the bench shape).
    for (; i < n4; i += stride) {
        int4 pv = preds[i];
        int4 tv = targs[i];
        process_vec(pv, tv, s_col);
    }
    __syncthreads();

    // Block reduction: 4 waves, wave w handles classes w, w+4, ..., <NB.
    const int wid  = tid >> 6;
    const int lane = tid & 63;
    unsigned* dst = &partials[(size_t)blockIdx.x * PSTRIDE];
    for (int c = wid; c < NB; c += (BLK / 64)) {
        unsigned sp = 0, st = 0, si = 0;
        #pragma unroll
        for (int k = 0; k < BLK / 64; ++k) {
            unsigned v = s_hist[c * BLK + k * 64 + lane];
            sp += v & 1023u;
            st += (v >> 10) & 1023u;
            si += (v >> 20) & 1023u;
        }
        #pragma unroll
        for (int off = 32; off > 0; off >>= 1) {
            sp += __shfl_xor(sp, off);
            st += __shfl_xor(st, off);
            si += __shfl_xor(si, off);
        }
        if (lane == 0) {
            dst[c]          = sp;
            dst[NB + c]     = st;
            dst[2 * NB + c] = si;
        }
    }
}

// One block, 1024 threads. partials = nblocks rows x 16 int4 (coalesced).
__global__ __launch_bounds__(1024) void miou_reduce_kernel(
        const unsigned* __restrict__ partials, int nblocks,
        const int* __restrict__ nb_ptr, const int* __restrict__ smooth_ptr,
        float* __restrict__ out) {
    __shared__ unsigned s_tot[PSTRIDE];
    if (threadIdx.x < PSTRIDE) s_tot[threadIdx.x] = 0u;
    __syncthreads();

    const int col4 = threadIdx.x & 15;   // int4 column 0..15
    const int seg  = threadIdx.x >> 4;   // 64 row-segments
    const int4* p4 = (const int4*)partials;

    unsigned ax = 0, ay = 0, az = 0, aw = 0;
    #pragma unroll 8
    for (int r = seg; r < nblocks; r += 64) {
        int4 v = p4[r * 16 + col4];      // addr = tid + k*1024: coalesced
        ax += (unsigned)v.x; ay += (unsigned)v.y;
        az += (unsigned)v.z; aw += (unsigned)v.w;
    }
    atomicAdd(&s_tot[col4 * 4 + 0], ax);
    atomicAdd(&s_tot[col4 * 4 + 1], ay);
    atomicAdd(&s_tot[col4 * 4 + 2], az);
    atomicAdd(&s_tot[col4 * 4 + 3], aw);
    __syncthreads();

    if (threadIdx.x == 0) {
        const int   nb = *nb_ptr;
        const float s  = (float)(*smooth_ptr);
        float acc_iou = 0.0f;
        for (int c = 0; c < nb && c < NB; ++c) {
            float pc    = (float)s_tot[c];
            float tc    = (float)s_tot[NB + c];
            float inter = (float)s_tot[2 * NB + c];
            float uni   = pc + tc - inter;
            acc_iou += (inter + s) / (uni + s);
        }
        out[0] = 1.0f - acc_iou / (float)nb;
    }
}

extern "C" void kernel_launch(void* const* d_in, const int* in_sizes, int n_in,
                              void* d_out, int out_size, void* d_ws, size_t ws_size,
                              hipStream_t stream) {
    const int4* preds      = (const int4*)d_in[0];
    const int4* targs      = (const int4*)d_in[1];
    const int*  nb_ptr     = (const int*)d_in[2];
    const int*  smooth_ptr = (const int*)d_in[3];
    float*      out        = (float*)d_out;

    int n  = in_sizes[0];
    int n4 = n >> 2;  // 16M pixels, divisible by 4

    unsigned* partials = (unsigned*)d_ws;

    int grid = GRIDH;
    int max_grid = (n4 + BLK - 1) / BLK;
    if (grid > max_grid) grid = max_grid;
    size_t need_per_block = PSTRIDE * sizeof(unsigned);
    if ((size_t)grid * need_per_block > ws_size)
        grid = (int)(ws_size / need_per_block);

    miou_hist_kernel<<<grid, BLK, 0, stream>>>(preds, targs, partials, n4);
    miou_reduce_kernel<<<1, 1024, 0, stream>>>(partials, grid, nb_ptr, smooth_ptr, out);
}